// Round 1
// baseline (9400.610 us; speedup 1.0000x reference)
//
#include <hip/hip_runtime.h>
#include <hip/hip_bf16.h>
#include <math.h>

#define TT 1024
#define DD 768
#define HH 12
#define LL 4
#define BB 2
#define VV 50257
#define NROWS (BB * TT)   // 2048

// ---------------------------------------------------------------------------
// Embedding: x[n,d] = tok_emb[ids[n],d] + pos_emb[n%T,d]
// ---------------------------------------------------------------------------
__global__ __launch_bounds__(256) void embed_kernel(
    const int* __restrict__ ids, const float* __restrict__ tok,
    const float* __restrict__ pos, float* __restrict__ x)
{
    int n = blockIdx.x;           // 0..2047
    int t = n % TT;
    int id = ids[n];
    const float* tr = tok + (size_t)id * DD;
    const float* pr = pos + (size_t)t * DD;
    float* xr = x + (size_t)n * DD;
    for (int i = threadIdx.x; i < DD; i += 256)
        xr[i] = tr[i] + pr[i];
}

// ---------------------------------------------------------------------------
// LayerNorm: one block (256 thr) per row, D=768 -> 3 elems/thread in regs
// ---------------------------------------------------------------------------
__global__ __launch_bounds__(256) void ln_kernel(
    const float* __restrict__ x, const float* __restrict__ w,
    const float* __restrict__ b, float* __restrict__ y)
{
    __shared__ float red[8];
    int row = blockIdx.x;
    int tid = threadIdx.x;
    const float* xr = x + (size_t)row * DD;
    float v0 = xr[tid], v1 = xr[tid + 256], v2 = xr[tid + 512];
    float s = v0 + v1 + v2;
    #pragma unroll
    for (int off = 32; off; off >>= 1) s += __shfl_xor(s, off);
    if ((tid & 63) == 0) red[tid >> 6] = s;
    __syncthreads();
    float mean = (red[0] + red[1] + red[2] + red[3]) * (1.0f / DD);
    float d0 = v0 - mean, d1 = v1 - mean, d2 = v2 - mean;
    float var = d0 * d0 + d1 * d1 + d2 * d2;
    #pragma unroll
    for (int off = 32; off; off >>= 1) var += __shfl_xor(var, off);
    if ((tid & 63) == 0) red[4 + (tid >> 6)] = var;
    __syncthreads();
    float rstd = rsqrtf((red[4] + red[5] + red[6] + red[7]) * (1.0f / DD) + 1e-5f);
    float* yr = y + (size_t)row * DD;
    yr[tid]       = d0 * rstd * w[tid]       + b[tid];
    yr[tid + 256] = d1 * rstd * w[tid + 256] + b[tid + 256];
    yr[tid + 512] = d2 * rstd * w[tid + 512] + b[tid + 512];
}

// ---------------------------------------------------------------------------
// fp32 tiled GEMM, A[N,K] row-major, B[K,M] row-major, C[N,M]
// BM=BN=64, BK=16, 256 threads, 4x4 acc/thread.
// EPI: 1 = +bias, 2 = +bias+residual, 3 = +bias+exact-GELU
// N multiple of 64, K multiple of 16, M multiple of 64 (guaranteed for nn).
// ---------------------------------------------------------------------------
template<int EPI>
__global__ __launch_bounds__(256) void gemm_nn(
    const float* __restrict__ A, const float* __restrict__ B,
    const float* __restrict__ bias, const float* __restrict__ res,
    float* __restrict__ C, int K, int M)
{
    __shared__ float As[16][64];
    __shared__ float Bs[16][64];
    int bm = blockIdx.y * 64;     // row offset (N dim)
    int bn = blockIdx.x * 64;     // col offset (M dim)
    int tid = threadIdx.x;
    int tx = tid & 15, ty = tid >> 4;
    int la_n = tid >> 2;          // 0..63
    int la_k = (tid & 3) * 4;     // 0,4,8,12
    int lb_k = tid >> 4;          // 0..15
    int lb_m = (tid & 15) * 4;    // 0..60

    float acc[4][4] = {};

    for (int k0 = 0; k0 < K; k0 += 16) {
        float4 av = *reinterpret_cast<const float4*>(&A[(size_t)(bm + la_n) * K + k0 + la_k]);
        As[la_k + 0][la_n] = av.x; As[la_k + 1][la_n] = av.y;
        As[la_k + 2][la_n] = av.z; As[la_k + 3][la_n] = av.w;
        float4 bv = *reinterpret_cast<const float4*>(&B[(size_t)(k0 + lb_k) * M + bn + lb_m]);
        *reinterpret_cast<float4*>(&Bs[lb_k][lb_m]) = bv;
        __syncthreads();
        #pragma unroll
        for (int kk = 0; kk < 16; ++kk) {
            float4 a4 = *reinterpret_cast<const float4*>(&As[kk][ty * 4]);
            float4 b4 = *reinterpret_cast<const float4*>(&Bs[kk][tx * 4]);
            float a[4] = {a4.x, a4.y, a4.z, a4.w};
            float b[4] = {b4.x, b4.y, b4.z, b4.w};
            #pragma unroll
            for (int i = 0; i < 4; ++i)
                #pragma unroll
                for (int j = 0; j < 4; ++j)
                    acc[i][j] += a[i] * b[j];
        }
        __syncthreads();
    }

    int row = bm + ty * 4;
    int col = bn + tx * 4;
    #pragma unroll
    for (int i = 0; i < 4; ++i) {
        #pragma unroll
        for (int j = 0; j < 4; ++j) {
            float v = acc[i][j] + bias[col + j];
            if (EPI == 2) v += res[(size_t)(row + i) * M + col + j];
            if (EPI == 3) v = 0.5f * v * (1.0f + erff(v * 0.70710678118654752f));
            C[(size_t)(row + i) * M + col + j] = v;
        }
    }
}

// ---------------------------------------------------------------------------
// fp32 tiled GEMM, A[N,K] row-major, B[M,K] row-major (B transposed), C[N,M]
// Used for logits = h @ tok_emb^T.  M bounds-checked (V=50257 not mult of 64).
// ---------------------------------------------------------------------------
__global__ __launch_bounds__(256) void gemm_bt(
    const float* __restrict__ A, const float* __restrict__ B,
    float* __restrict__ C, int K, int M)
{
    __shared__ float As[16][64];
    __shared__ float Bs[16][64];
    int bm = blockIdx.y * 64;
    int bn = blockIdx.x * 64;
    int tid = threadIdx.x;
    int tx = tid & 15, ty = tid >> 4;
    int la_n = tid >> 2;
    int la_k = (tid & 3) * 4;

    float acc[4][4] = {};

    for (int k0 = 0; k0 < K; k0 += 16) {
        float4 av = *reinterpret_cast<const float4*>(&A[(size_t)(bm + la_n) * K + k0 + la_k]);
        As[la_k + 0][la_n] = av.x; As[la_k + 1][la_n] = av.y;
        As[la_k + 2][la_n] = av.z; As[la_k + 3][la_n] = av.w;
        float4 bv = make_float4(0.f, 0.f, 0.f, 0.f);
        if (bn + la_n < M)
            bv = *reinterpret_cast<const float4*>(&B[(size_t)(bn + la_n) * K + k0 + la_k]);
        Bs[la_k + 0][la_n] = bv.x; Bs[la_k + 1][la_n] = bv.y;
        Bs[la_k + 2][la_n] = bv.z; Bs[la_k + 3][la_n] = bv.w;
        __syncthreads();
        #pragma unroll
        for (int kk = 0; kk < 16; ++kk) {
            float4 a4 = *reinterpret_cast<const float4*>(&As[kk][ty * 4]);
            float4 b4 = *reinterpret_cast<const float4*>(&Bs[kk][tx * 4]);
            float a[4] = {a4.x, a4.y, a4.z, a4.w};
            float b[4] = {b4.x, b4.y, b4.z, b4.w};
            #pragma unroll
            for (int i = 0; i < 4; ++i)
                #pragma unroll
                for (int j = 0; j < 4; ++j)
                    acc[i][j] += a[i] * b[j];
        }
        __syncthreads();
    }

    int row = bm + ty * 4;
    int col = bn + tx * 4;
    #pragma unroll
    for (int i = 0; i < 4; ++i)
        #pragma unroll
        for (int j = 0; j < 4; ++j)
            if (col + j < M)
                C[(size_t)(row + i) * M + col + j] = acc[i][j];
}

// ---------------------------------------------------------------------------
// Causal attention, flash-style: one wave per query row, lane = head dim.
// qkv layout: [N, 3*D], q|k|v each D, head h occupies 64 cols.
// ---------------------------------------------------------------------------
__global__ __launch_bounds__(256) void attn_kernel(
    const float* __restrict__ qkv, float* __restrict__ o)
{
    int wave = threadIdx.x >> 6;
    int lane = threadIdx.x & 63;
    int gid = blockIdx.x * 4 + wave;          // 0 .. B*H*T-1
    int b = gid / (HH * TT);
    int rem = gid - b * (HH * TT);
    int h = rem / TT;
    int t = rem - h * TT;

    int rowq = (b * TT + t) * 3 * DD + h * 64;
    float qv = qkv[rowq + lane] * 0.125f;     // 1/sqrt(64)

    float m = -3.0e38f, s = 0.0f, acc = 0.0f;
    for (int t2 = 0; t2 <= t; ++t2) {
        int base = (b * TT + t2) * 3 * DD + h * 64;
        float kv = qkv[base + DD + lane];
        float vv = qkv[base + 2 * DD + lane];
        float prod = qv * kv;
        #pragma unroll
        for (int off = 32; off; off >>= 1) prod += __shfl_xor(prod, off);
        float mn = fmaxf(m, prod);
        float p = __expf(prod - mn);
        float corr = __expf(m - mn);
        s = s * corr + p;
        acc = acc * corr + p * vv;
        m = mn;
    }
    o[(size_t)(b * TT + t) * DD + h * 64 + lane] = acc / s;
}

// ---------------------------------------------------------------------------
// Per-row cross-entropy: online max/sumexp over V, one block per row.
// ---------------------------------------------------------------------------
__global__ __launch_bounds__(256) void row_loss(
    const float* __restrict__ logits, const int* __restrict__ tgt,
    float* __restrict__ nll)
{
    int r = blockIdx.x;
    int tid = threadIdx.x;
    const float* lr = logits + (size_t)r * VV;
    float m = -3.0e38f, s = 0.0f;
    for (int v = tid; v < VV; v += 256) {
        float x = lr[v];
        float mn = fmaxf(m, x);
        s = s * __expf(m - mn) + __expf(x - mn);
        m = mn;
    }
    #pragma unroll
    for (int off = 32; off; off >>= 1) {
        float mo = __shfl_xor(m, off), so = __shfl_xor(s, off);
        float mn = fmaxf(m, mo);
        s = s * __expf(m - mn) + so * __expf(mo - mn);
        m = mn;
    }
    __shared__ float sm[4], ss[4];
    if ((tid & 63) == 0) { sm[tid >> 6] = m; ss[tid >> 6] = s; }
    __syncthreads();
    if (tid == 0) {
        float M = fmaxf(fmaxf(sm[0], sm[1]), fmaxf(sm[2], sm[3]));
        float S = ss[0] * __expf(sm[0] - M) + ss[1] * __expf(sm[1] - M)
                + ss[2] * __expf(sm[2] - M) + ss[3] * __expf(sm[3] - M);
        int t = tgt[r];
        nll[r] = (t != -1) ? -(lr[t] - M - logf(S)) : 0.0f;
    }
}

__global__ __launch_bounds__(256) void loss_reduce(
    const float* __restrict__ nll, const int* __restrict__ tgt,
    float* __restrict__ out, int n)
{
    int tid = threadIdx.x;
    float s = 0.0f, c = 0.0f;
    for (int i = tid; i < n; i += 256) {
        s += nll[i];
        c += (tgt[i] != -1) ? 1.0f : 0.0f;
    }
    #pragma unroll
    for (int off = 32; off; off >>= 1) {
        s += __shfl_xor(s, off);
        c += __shfl_xor(c, off);
    }
    __shared__ float sv[4], cv[4];
    if ((tid & 63) == 0) { sv[tid >> 6] = s; cv[tid >> 6] = c; }
    __syncthreads();
    if (tid == 0) {
        float S = sv[0] + sv[1] + sv[2] + sv[3];
        float C = cv[0] + cv[1] + cv[2] + cv[3];
        out[0] = S / fmaxf(C, 1.0f);
    }
}

// ---------------------------------------------------------------------------
extern "C" void kernel_launch(void* const* d_in, const int* in_sizes, int n_in,
                              void* d_out, int out_size, void* d_ws, size_t ws_size,
                              hipStream_t stream)
{
    const int*   ids  = (const int*)  d_in[0];
    const int*   tgt  = (const int*)  d_in[1];
    const float* tok  = (const float*)d_in[2];
    const float* pos  = (const float*)d_in[3];
    const float* ln1w = (const float*)d_in[4];
    const float* ln1b = (const float*)d_in[5];
    const float* qkvw = (const float*)d_in[6];
    const float* qkvb = (const float*)d_in[7];
    const float* apw  = (const float*)d_in[8];
    const float* apb  = (const float*)d_in[9];
    const float* ln2w = (const float*)d_in[10];
    const float* ln2b = (const float*)d_in[11];
    const float* fcw  = (const float*)d_in[12];
    const float* fcb  = (const float*)d_in[13];
    const float* pjw  = (const float*)d_in[14];
    const float* pjb  = (const float*)d_in[15];
    const float* lnfw = (const float*)d_in[16];
    const float* lnfb = (const float*)d_in[17];

    float* out    = (float*)d_out;
    float* logits = out + 1;                  // [B*T, V]

    const size_t ND = (size_t)NROWS * DD;     // 1572864
    float* ws  = (float*)d_ws;
    float* x   = ws;                          // [N, D]
    float* h   = ws + ND;                     // [N, D]
    float* ao  = ws + 2 * ND;                 // [N, D]
    float* big = ws + 3 * ND;                 // [N, 3072] shared qkv/fc buffer
    float* nll = ws + 3 * ND + (size_t)NROWS * 4 * DD;  // [N]

    embed_kernel<<<NROWS, 256, 0, stream>>>(ids, tok, pos, x);

    for (int l = 0; l < LL; ++l) {
        // LN1 -> h
        ln_kernel<<<NROWS, 256, 0, stream>>>(x, ln1w + l * DD, ln1b + l * DD, h);
        // qkv = h @ qkv_w + b  -> big [N, 2304]
        gemm_nn<1><<<dim3(36, 32), 256, 0, stream>>>(
            h, qkvw + (size_t)l * DD * 3 * DD, qkvb + (size_t)l * 3 * DD,
            nullptr, big, DD, 3 * DD);
        // attention -> ao [N, D]
        attn_kernel<<<(BB * HH * TT) / 4, 256, 0, stream>>>(big, ao);
        // x = x + ao @ attn_proj_w + b
        gemm_nn<2><<<dim3(12, 32), 256, 0, stream>>>(
            ao, apw + (size_t)l * DD * DD, apb + (size_t)l * DD, x, x, DD, DD);
        // LN2 -> h
        ln_kernel<<<NROWS, 256, 0, stream>>>(x, ln2w + l * DD, ln2b + l * DD, h);
        // fc = gelu(h @ fc_w + b) -> big [N, 3072]
        gemm_nn<3><<<dim3(48, 32), 256, 0, stream>>>(
            h, fcw + (size_t)l * DD * 4 * DD, fcb + (size_t)l * 4 * DD,
            nullptr, big, DD, 4 * DD);
        // x = x + fc @ proj_w + b
        gemm_nn<2><<<dim3(12, 32), 256, 0, stream>>>(
            big, pjw + (size_t)l * 4 * DD * DD, pjb + (size_t)l * DD, x, x,
            4 * DD, DD);
    }

    // final LN -> h
    ln_kernel<<<NROWS, 256, 0, stream>>>(x, lnfw, lnfb, h);
    // logits = h @ tok^T  -> d_out+1
    gemm_bt<<<dim3((VV + 63) / 64, 32), 256, 0, stream>>>(h, tok, logits, DD, VV);
    // loss
    row_loss<<<NROWS, 256, 0, stream>>>(logits, tgt, nll);
    loss_reduce<<<1, 256, 0, stream>>>(nll, tgt, out, NROWS);
}

// Round 4
// 5037.717 us; speedup vs baseline: 1.8660x; 1.8660x over previous
//
#include <hip/hip_runtime.h>
#include <hip/hip_bf16.h>
#include <math.h>

#define TT 1024
#define DD 768
#define HH 12
#define LL 4
#define BB 2
#define VV 50257
#define NROWS (BB * TT)   // 2048

typedef __attribute__((ext_vector_type(8))) short bf16x8;
typedef __attribute__((ext_vector_type(8))) unsigned short u16x8;
typedef __attribute__((ext_vector_type(4))) float f32x4;

// bf16 <-> f32 (RNE), bit-level to avoid type friction
__device__ __forceinline__ unsigned short f2b(float f) {
    unsigned int u = __float_as_uint(f);
    unsigned int r = (u + 0x7fffu + ((u >> 16) & 1u)) >> 16;
    return (unsigned short)r;
}
__device__ __forceinline__ float b2f(unsigned short u) {
    return __uint_as_float(((unsigned int)u) << 16);
}

__device__ __forceinline__ void gl_lds16(const void* g, void* l) {
    __builtin_amdgcn_global_load_lds(
        (const __attribute__((address_space(1))) void*)g,
        (__attribute__((address_space(3))) void*)l, 16, 0, 0);
}

// ---------------------------------------------------------------------------
// Embedding: x[n,d] = tok_emb[ids[n],d] + pos_emb[n%T,d]  (fp32)
// ---------------------------------------------------------------------------
__global__ __launch_bounds__(256) void embed_kernel(
    const int* __restrict__ ids, const float* __restrict__ tok,
    const float* __restrict__ pos, float* __restrict__ x)
{
    int n = blockIdx.x;
    int t = n % TT;
    int id = ids[n];
    const float* tr = tok + (size_t)id * DD;
    const float* pr = pos + (size_t)t * DD;
    float* xr = x + (size_t)n * DD;
    for (int i = threadIdx.x; i < DD; i += 256)
        xr[i] = tr[i] + pr[i];
}

// ---------------------------------------------------------------------------
// Weight transpose+convert: W[K][M] fp32 -> Wt[M][K] bf16, 32x32 tiles
// ---------------------------------------------------------------------------
__global__ __launch_bounds__(256) void wtrans(
    const float* __restrict__ W, unsigned short* __restrict__ Wt, int K, int M)
{
    __shared__ float t[32][33];
    int m0 = blockIdx.x * 32, k0 = blockIdx.y * 32;
    int c = threadIdx.x & 31, r0 = threadIdx.x >> 5;   // 8 rows/pass
    #pragma unroll
    for (int i = 0; i < 4; ++i)
        t[r0 + i * 8][c] = W[(size_t)(k0 + r0 + i * 8) * M + m0 + c];
    __syncthreads();
    #pragma unroll
    for (int i = 0; i < 4; ++i) {
        int r = r0 + i * 8;
        Wt[(size_t)(m0 + r) * K + k0 + c] = f2b(t[c][r]);
    }
}

// ---------------------------------------------------------------------------
// LayerNorm: fp32 in, bf16 out. One block per row.
// ---------------------------------------------------------------------------
__global__ __launch_bounds__(256) void ln_kernel(
    const float* __restrict__ x, const float* __restrict__ w,
    const float* __restrict__ b, unsigned short* __restrict__ y)
{
    __shared__ float red[8];
    int row = blockIdx.x;
    int tid = threadIdx.x;
    const float* xr = x + (size_t)row * DD;
    float v0 = xr[tid], v1 = xr[tid + 256], v2 = xr[tid + 512];
    float s = v0 + v1 + v2;
    #pragma unroll
    for (int off = 32; off; off >>= 1) s += __shfl_xor(s, off);
    if ((tid & 63) == 0) red[tid >> 6] = s;
    __syncthreads();
    float mean = (red[0] + red[1] + red[2] + red[3]) * (1.0f / DD);
    float d0 = v0 - mean, d1 = v1 - mean, d2 = v2 - mean;
    float var = d0 * d0 + d1 * d1 + d2 * d2;
    #pragma unroll
    for (int off = 32; off; off >>= 1) var += __shfl_xor(var, off);
    if ((tid & 63) == 0) red[4 + (tid >> 6)] = var;
    __syncthreads();
    float rstd = rsqrtf((red[4] + red[5] + red[6] + red[7]) * (1.0f / DD) + 1e-5f);
    unsigned short* yr = y + (size_t)row * DD;
    yr[tid]       = f2b(d0 * rstd * w[tid]       + b[tid]);
    yr[tid + 256] = f2b(d1 * rstd * w[tid + 256] + b[tid + 256]);
    yr[tid + 512] = f2b(d2 * rstd * w[tid + 512] + b[tid + 512]);
}

// ---------------------------------------------------------------------------
// bf16 MFMA GEMM (m97 structure): C[N,M] = A[N,K] * Bt[M,K]^T
// 128x128 tile, BK=32, 4 waves (2x2), 16x16x32 MFMA, fp32 accum.
// EPI: 0 = +bias -> bf16 out
//      1 = +bias + exact GELU -> bf16 out
//      2 = +bias, add into fp32 residual Cf
// N % 128 == 0, K % 32 == 0, M % 128 == 0.
// ---------------------------------------------------------------------------
template<int EPI>
__global__ __launch_bounds__(256) void gemm_mfma(
    const unsigned short* __restrict__ A, const unsigned short* __restrict__ Bt,
    const float* __restrict__ bias, float* __restrict__ Cf,
    unsigned short* __restrict__ Cb, int K, int M)
{
    __shared__ __align__(16) short As[128 * 32];
    __shared__ __align__(16) short Bs[128 * 32];
    int tid = threadIdx.x;
    int wid = tid >> 6, lane = tid & 63;
    int n0 = blockIdx.y * 128;
    int m0 = blockIdx.x * 128;

    // staging: thread -> (row = tid/4, k8 = tid%4), 2 row-halves each for A,B
    int srow = tid >> 2;
    int sk = (tid & 3) * 8;
    const unsigned short* Ag0 = A + (size_t)(n0 + srow) * K + sk;
    const unsigned short* Ag1 = A + (size_t)(n0 + 64 + srow) * K + sk;
    const unsigned short* Bg0 = Bt + (size_t)(m0 + srow) * K + sk;
    const unsigned short* Bg1 = Bt + (size_t)(m0 + 64 + srow) * K + sk;
    short* Al0 = As + wid * 512;           // wave-uniform LDS bases
    short* Al1 = As + 2048 + wid * 512;
    short* Bl0 = Bs + wid * 512;
    short* Bl1 = Bs + 2048 + wid * 512;

    f32x4 acc[4][4] = {};
    int wm = wid >> 1, wn = wid & 1;
    int fr = lane & 15, fk = (lane >> 4) * 8;
    int arow = wm * 64 + fr;
    int brow = wn * 64 + fr;

    for (int k0 = 0; k0 < K; k0 += 32) {
        gl_lds16(Ag0 + k0, Al0);
        gl_lds16(Ag1 + k0, Al1);
        gl_lds16(Bg0 + k0, Bl0);
        gl_lds16(Bg1 + k0, Bl1);
        __syncthreads();
        bf16x8 af[4], bfv[4];
        #pragma unroll
        for (int m = 0; m < 4; ++m)
            af[m] = *reinterpret_cast<const bf16x8*>(&As[(arow + m * 16) * 32 + fk]);
        #pragma unroll
        for (int n = 0; n < 4; ++n)
            bfv[n] = *reinterpret_cast<const bf16x8*>(&Bs[(brow + n * 16) * 32 + fk]);
        #pragma unroll
        for (int m = 0; m < 4; ++m)
            #pragma unroll
            for (int n = 0; n < 4; ++n)
                acc[m][n] = __builtin_amdgcn_mfma_f32_16x16x32_bf16(
                    af[m], bfv[n], acc[m][n], 0, 0, 0);
        __syncthreads();
    }

    // epilogue: C[row=(lane>>4)*4+r][col=lane&15] per 16x16 fragment
    int ccol0 = m0 + wn * 64 + fr;
    int crow0 = n0 + wm * 64 + (lane >> 4) * 4;
    #pragma unroll
    for (int n = 0; n < 4; ++n) {
        int col = ccol0 + n * 16;
        float bv = bias[col];
        #pragma unroll
        for (int m = 0; m < 4; ++m) {
            #pragma unroll
            for (int r = 0; r < 4; ++r) {
                int row = crow0 + m * 16 + r;
                float o = acc[m][n][r] + bv;
                size_t idx = (size_t)row * M + col;
                if (EPI == 0) {
                    Cb[idx] = f2b(o);
                } else if (EPI == 1) {
                    o = 0.5f * o * (1.0f + erff(o * 0.70710678118654752f));
                    Cb[idx] = f2b(o);
                } else {
                    Cf[idx] += o;
                }
            }
        }
    }
}

// ---------------------------------------------------------------------------
// Logits GEMM: C[N,M] = A[N,K](bf16) * Bf[M,K](fp32)^T, fp32 out.
// Same 128x128/BK=32 MFMA structure; B staged via regs with fp32->bf16
// conversion (tok_emb read directly, no 77MB bf16 copy). M bounds-checked.
// ---------------------------------------------------------------------------
__global__ __launch_bounds__(256) void gemm_logits(
    const unsigned short* __restrict__ A, const float* __restrict__ Bf,
    float* __restrict__ Cf, int K, int M)
{
    __shared__ __align__(16) short As[128 * 32];
    __shared__ __align__(16) short Bs[128 * 32];
    int tid = threadIdx.x;
    int wid = tid >> 6, lane = tid & 63;
    int n0 = blockIdx.y * 128;
    int m0 = blockIdx.x * 128;

    int srow = tid >> 2;
    int sk = (tid & 3) * 8;
    const unsigned short* Ag0 = A + (size_t)(n0 + srow) * K + sk;
    const unsigned short* Ag1 = A + (size_t)(n0 + 64 + srow) * K + sk;
    int br0 = min(m0 + srow, M - 1);
    int br1 = min(m0 + 64 + srow, M - 1);
    const float* Bg0 = Bf + (size_t)br0 * K + sk;
    const float* Bg1 = Bf + (size_t)br1 * K + sk;
    short* Al0 = As + wid * 512;
    short* Al1 = As + 2048 + wid * 512;
    u16x8* Bl0 = reinterpret_cast<u16x8*>(&Bs[srow * 32 + sk]);
    u16x8* Bl1 = reinterpret_cast<u16x8*>(&Bs[(64 + srow) * 32 + sk]);

    f32x4 acc[4][4] = {};
    int wm = wid >> 1, wn = wid & 1;
    int fr = lane & 15, fk = (lane >> 4) * 8;
    int arow = wm * 64 + fr;
    int brow = wn * 64 + fr;

    for (int k0 = 0; k0 < K; k0 += 32) {
        gl_lds16(Ag0 + k0, Al0);
        gl_lds16(Ag1 + k0, Al1);
        float4 b0a = *reinterpret_cast<const float4*>(Bg0 + k0);
        float4 b0b = *reinterpret_cast<const float4*>(Bg0 + k0 + 4);
        float4 b1a = *reinterpret_cast<const float4*>(Bg1 + k0);
        float4 b1b = *reinterpret_cast<const float4*>(Bg1 + k0 + 4);
        u16x8 p0, p1;
        p0[0] = f2b(b0a.x); p0[1] = f2b(b0a.y); p0[2] = f2b(b0a.z); p0[3] = f2b(b0a.w);
        p0[4] = f2b(b0b.x); p0[5] = f2b(b0b.y); p0[6] = f2b(b0b.z); p0[7] = f2b(b0b.w);
        p1[0] = f2b(b1a.x); p1[1] = f2b(b1a.y); p1[2] = f2b(b1a.z); p1[3] = f2b(b1a.w);
        p1[4] = f2b(b1b.x); p1[5] = f2b(b1b.y); p1[6] = f2b(b1b.z); p1[7] = f2b(b1b.w);
        *Bl0 = p0;
        *Bl1 = p1;
        __syncthreads();
        bf16x8 af[4], bfv[4];
        #pragma unroll
        for (int m = 0; m < 4; ++m)
            af[m] = *reinterpret_cast<const bf16x8*>(&As[(arow + m * 16) * 32 + fk]);
        #pragma unroll
        for (int n = 0; n < 4; ++n)
            bfv[n] = *reinterpret_cast<const bf16x8*>(&Bs[(brow + n * 16) * 32 + fk]);
        #pragma unroll
        for (int m = 0; m < 4; ++m)
            #pragma unroll
            for (int n = 0; n < 4; ++n)
                acc[m][n] = __builtin_amdgcn_mfma_f32_16x16x32_bf16(
                    af[m], bfv[n], acc[m][n], 0, 0, 0);
        __syncthreads();
    }

    int ccol0 = m0 + wn * 64 + fr;
    int crow0 = n0 + wm * 64 + (lane >> 4) * 4;
    #pragma unroll
    for (int n = 0; n < 4; ++n) {
        int col = ccol0 + n * 16;
        if (col < M) {
            #pragma unroll
            for (int m = 0; m < 4; ++m)
                #pragma unroll
                for (int r = 0; r < 4; ++r) {
                    int row = crow0 + m * 16 + r;
                    Cf[(size_t)row * M + col] = acc[m][n][r];
                }
        }
    }
}

// ---------------------------------------------------------------------------
// Causal attention, flash-style, bf16 qkv in / bf16 out, fp32 math.
// One wave per query row; keys processed 8 per iteration.
// grid (B*H, T/4), block 256 (4 waves).
// ---------------------------------------------------------------------------
__global__ __launch_bounds__(256) void attn_kernel(
    const unsigned short* __restrict__ qkv, unsigned short* __restrict__ o)
{
    int wave = threadIdx.x >> 6, lane = threadIdx.x & 63;
    int bh = blockIdx.x;
    int b = bh / HH, h = bh % HH;
    int t = blockIdx.y * 4 + wave;

    const unsigned short* base = qkv + (size_t)b * TT * 2304 + h * 64 + lane;
    float qv = b2f(base[(size_t)t * 2304]) * 0.125f;   // 1/sqrt(64)
    const unsigned short* Kp = base + 768;
    const unsigned short* Vp = base + 1536;

    float m = -3.0e38f, s = 0.0f, acc = 0.0f;
    int t2 = 0;
    for (; t2 + 8 <= t + 1; t2 += 8) {
        float p[8];
        #pragma unroll
        for (int j = 0; j < 8; ++j)
            p[j] = qv * b2f(Kp[(size_t)(t2 + j) * 2304]);
        #pragma unroll
        for (int j = 0; j < 8; ++j) {
            float v = p[j];
            #pragma unroll
            for (int off = 32; off; off >>= 1) v += __shfl_xor(v, off);
            p[j] = v;
        }
        float mx = m;
        #pragma unroll
        for (int j = 0; j < 8; ++j) mx = fmaxf(mx, p[j]);
        float corr = __expf(m - mx);
        float sum = 0.0f, av = 0.0f;
        #pragma unroll
        for (int j = 0; j < 8; ++j) {
            float e = __expf(p[j] - mx);
            sum += e;
            av += e * b2f(Vp[(size_t)(t2 + j) * 2304]);
        }
        s = s * corr + sum;
        acc = acc * corr + av;
        m = mx;
    }
    for (; t2 <= t; ++t2) {
        float v = qv * b2f(Kp[(size_t)t2 * 2304]);
        #pragma unroll
        for (int off = 32; off; off >>= 1) v += __shfl_xor(v, off);
        float mx = fmaxf(m, v);
        float corr = __expf(m - mx);
        float e = __expf(v - mx);
        s = s * corr + e;
        acc = acc * corr + e * b2f(Vp[(size_t)t2 * 2304]);
        m = mx;
    }
    o[((size_t)(b * TT + t)) * DD + h * 64 + lane] = f2b(acc / s);
}

// ---------------------------------------------------------------------------
// Per-row cross-entropy over V (online max/sumexp), then mean-reduce.
// ---------------------------------------------------------------------------
__global__ __launch_bounds__(256) void row_loss(
    const float* __restrict__ logits, const int* __restrict__ tgt,
    float* __restrict__ nll)
{
    int r = blockIdx.x;
    int tid = threadIdx.x;
    const float* lr = logits + (size_t)r * VV;
    float m = -3.0e38f, s = 0.0f;
    for (int v = tid; v < VV; v += 256) {
        float x = lr[v];
        float mn = fmaxf(m, x);
        s = s * __expf(m - mn) + __expf(x - mn);
        m = mn;
    }
    #pragma unroll
    for (int off = 32; off; off >>= 1) {
        float mo = __shfl_xor(m, off), so = __shfl_xor(s, off);
        float mn = fmaxf(m, mo);
        s = s * __expf(m - mn) + so * __expf(mo - mn);
        m = mn;
    }
    __shared__ float sm[4], ss[4];
    if ((tid & 63) == 0) { sm[tid >> 6] = m; ss[tid >> 6] = s; }
    __syncthreads();
    if (tid == 0) {
        float M = fmaxf(fmaxf(sm[0], sm[1]), fmaxf(sm[2], sm[3]));
        float S = ss[0] * __expf(sm[0] - M) + ss[1] * __expf(sm[1] - M)
                + ss[2] * __expf(sm[2] - M) + ss[3] * __expf(sm[3] - M);
        int t = tgt[r];
        nll[r] = (t != -1) ? -(lr[t] - M - logf(S)) : 0.0f;
    }
}

__global__ __launch_bounds__(256) void loss_reduce(
    const float* __restrict__ nll, const int* __restrict__ tgt,
    float* __restrict__ out, int n)
{
    int tid = threadIdx.x;
    float s = 0.0f, c = 0.0f;
    for (int i = tid; i < n; i += 256) {
        s += nll[i];
        c += (tgt[i] != -1) ? 1.0f : 0.0f;
    }
    #pragma unroll
    for (int off = 32; off; off >>= 1) {
        s += __shfl_xor(s, off);
        c += __shfl_xor(c, off);
    }
    __shared__ float sv[4], cv[4];
    if ((tid & 63) == 0) { sv[tid >> 6] = s; cv[tid >> 6] = c; }
    __syncthreads();
    if (tid == 0) {
        float S = sv[0] + sv[1] + sv[2] + sv[3];
        float C = cv[0] + cv[1] + cv[2] + cv[3];
        out[0] = S / fmaxf(C, 1.0f);
    }
}

// ---------------------------------------------------------------------------
extern "C" void kernel_launch(void* const* d_in, const int* in_sizes, int n_in,
                              void* d_out, int out_size, void* d_ws, size_t ws_size,
                              hipStream_t stream)
{
    const int*   ids  = (const int*)  d_in[0];
    const int*   tgt  = (const int*)  d_in[1];
    const float* tok  = (const float*)d_in[2];
    const float* pos  = (const float*)d_in[3];
    const float* ln1w = (const float*)d_in[4];
    const float* ln1b = (const float*)d_in[5];
    const float* qkvw = (const float*)d_in[6];
    const float* qkvb = (const float*)d_in[7];
    const float* apw  = (const float*)d_in[8];
    const float* apb  = (const float*)d_in[9];
    const float* ln2w = (const float*)d_in[10];
    const float* ln2b = (const float*)d_in[11];
    const float* fcw  = (const float*)d_in[12];
    const float* fcb  = (const float*)d_in[13];
    const float* pjw  = (const float*)d_in[14];
    const float* pjb  = (const float*)d_in[15];
    const float* lnfw = (const float*)d_in[16];
    const float* lnfb = (const float*)d_in[17];

    float* out    = (float*)d_out;
    float* logits = out + 1;                      // [N, V] fp32

    const size_t ND = (size_t)NROWS * DD;         // 1,572,864
    float* x   = (float*)d_ws;                    // [N,D] fp32 residual
    float* nll = x + ND;                          // [N] fp32
    unsigned short* h    = (unsigned short*)(nll + NROWS);   // [N,D] bf16
    unsigned short* ao   = h + ND;                           // [N,D] bf16
    unsigned short* big  = ao + ND;                          // [N,3072] bf16
    unsigned short* qkvT = big + (size_t)NROWS * 3072;       // [2304,768]
    unsigned short* apT  = qkvT + (size_t)2304 * 768;        // [768,768]
    unsigned short* fcT  = apT + (size_t)768 * 768;          // [3072,768]
    unsigned short* pjT  = fcT + (size_t)768 * 3072;         // [768,3072]
    // total ws: ~39 MB

    embed_kernel<<<NROWS, 256, 0, stream>>>(ids, tok, pos, x);

    for (int l = 0; l < LL; ++l) {
        // per-layer weights -> bf16 transposed [M][K]
        wtrans<<<dim3(2304 / 32, 768 / 32), 256, 0, stream>>>(
            qkvw + (size_t)l * 768 * 2304, qkvT, 768, 2304);
        wtrans<<<dim3(768 / 32, 768 / 32), 256, 0, stream>>>(
            apw + (size_t)l * 768 * 768, apT, 768, 768);
        wtrans<<<dim3(3072 / 32, 768 / 32), 256, 0, stream>>>(
            fcw + (size_t)l * 768 * 3072, fcT, 768, 3072);
        wtrans<<<dim3(768 / 32, 3072 / 32), 256, 0, stream>>>(
            pjw + (size_t)l * 3072 * 768, pjT, 3072, 768);

        ln_kernel<<<NROWS, 256, 0, stream>>>(x, ln1w + l * DD, ln1b + l * DD, h);
        gemm_mfma<0><<<dim3(18, 16), 256, 0, stream>>>(
            h, qkvT, qkvb + (size_t)l * 3 * DD, nullptr, big, DD, 3 * DD);
        attn_kernel<<<dim3(BB * HH, TT / 4), 256, 0, stream>>>(big, ao);
        gemm_mfma<2><<<dim3(6, 16), 256, 0, stream>>>(
            ao, apT, apb + (size_t)l * DD, x, nullptr, DD, DD);
        ln_kernel<<<NROWS, 256, 0, stream>>>(x, ln2w + l * DD, ln2b + l * DD, h);
        gemm_mfma<1><<<dim3(24, 16), 256, 0, stream>>>(
            h, fcT, fcb + (size_t)l * 4 * DD, nullptr, big, DD, 4 * DD);
        gemm_mfma<2><<<dim3(6, 16), 256, 0, stream>>>(
            big, pjT, pjb + (size_t)l * DD, x, nullptr, 4 * DD, DD);
    }

    ln_kernel<<<NROWS, 256, 0, stream>>>(x, lnfw, lnfb, h);
    gemm_logits<<<dim3((VV + 127) / 128, 16), 256, 0, stream>>>(
        h, tok, logits, DD, VV);

    row_loss<<<NROWS, 256, 0, stream>>>(logits, tgt, nll);
    loss_reduce<<<1, 256, 0, stream>>>(nll, tgt, out, NROWS);
}